// Round 7
// baseline (263.701 us; speedup 1.0000x reference)
//
#include <hip/hip_runtime.h>
#include <hip/hip_fp16.h>

// Deformable Conv2d — MI355X, round 7
// vs round 6: 512-thread blocks process TWO output rows sharing one 13-row
// LDS window (53.4 KB). 3 blocks/CU still fit -> 24 waves/CU (was 12), and
// staging cost per output row halves. Sample path trimmed (pre-clamped rows,
// factored weights, sigmoid hoisted into the burst).

#define KSZ 3
#define PAD 1

static constexpr int B   = 4;
static constexpr int Cin = 64;
static constexpr int H   = 256;
static constexpr int W   = 256;
static constexpr int G   = 8;
static constexpr int OC  = 64;
static constexpr int KK  = KSZ * KSZ;  // 9
static constexpr int Cpg = Cin / G;    // 8
static constexpr int OPG = OC / G;     // 8
static constexpr int HW  = H * W;
static constexpr int NXCD = 8;

static constexpr int WROWS  = 13;      // window rows: h_base-5 .. h_base+7
static constexpr int WUP    = 5;
static constexpr int WPITCH = 257;     // 16B slots/row; 257%8==1 rotates banks per row

typedef _Float16 f16x8  __attribute__((ext_vector_type(8)));
typedef float    f32x16 __attribute__((ext_vector_type(16)));

union U4H {
    uint4 u;
    __half2 h2[4];
    _Float16 h[8];
    f16x8 v;
};

// ---- transpose: x [B,Cin,H,W] f32 -> xt [B,G,H,W,Cpg] fp16 (16B/pixel) ----
__global__ __launch_bounds__(256) void transpose_kernel(
    const float* __restrict__ x, uint4* __restrict__ xt)
{
    const int h = blockIdx.x, g = blockIdx.y, b = blockIdx.z;
    const int w = threadIdx.x;
    const int pix = h * W + w;
    const float* src = x + (size_t)(b * Cin + g * Cpg) * HW + pix;
    U4H v;
#pragma unroll
    for (int c = 0; c < 8; ++c) v.h[c] = (_Float16)src[(size_t)c * HW];
    xt[(size_t)(b * G + g) * HW + pix] = v.u;
}

// ---- main kernel: 512 threads, 2 output rows/block ----
__global__ __launch_bounds__(512, 6) void dcn_kernel(
    const uint4* __restrict__ xt,
    const float* __restrict__ offset,
    const float* __restrict__ mask,
    const float* __restrict__ weight,
    const float* __restrict__ bias,
    float* __restrict__ out)
{
    __shared__ uint4 win[WROWS * WPITCH];   // 53,456 B -> 3 blocks/CU

    // XCD-chunked bijective swizzle over 4096 blocks (4096 % 8 == 0)
    const unsigned id = blockIdx.x;
    const unsigned wl = (id & (NXCD - 1)) * (gridDim.x / NXCD) + (id >> 3);
    const int p  = wl & (H / 2 - 1);          // row-pair index
    const int bg = wl >> 7;
    const int g  = bg & (G - 1);
    const int b  = bg >> 3;
    const int h_base = 2 * p;

    const int tid  = threadIdx.x;
    const int lane = tid & 63;
    const int wave = tid >> 6;                // 0..7
    const int row_sel = wave >> 2;            // 0 or 1 -> output row
    const int wv   = wave & 3;                // quarter within the row
    const int hi   = lane >> 5;               // tap parity in MFMA k dim
    const int lp   = lane & 31;               // A-row (out ch) / B-col (pixel)

    const int h  = h_base + row_sel;
    const int h0 = h_base - WUP;

    const uint4* xb = xt + (size_t)(b * G + g) * HW;

    // ---- stage the 13-row window (rows pre-clamped) ----
#pragma unroll
    for (int it = 0; it < 7; ++it) {
        const int k = it * 512 + tid;
        if (k < WROWS * 256) {
            const int i   = k >> 8;
            const int col = k & 255;
            const int wr  = min(max(h0 + i, 0), H - 1);
            win[i * WPITCH + col] = xb[wr * W + col];
        }
    }

    // A-fragments: weights, A[row=d][k=hi*8+c] -> tap 2m+hi, channel c.
    f16x8 afrag[5];
#pragma unroll
    for (int m = 0; m < 5; ++m) {
        f16x8 a = {};
        const int t = 2 * m + hi;
        if (lp < OPG && t < KK) {
            const float* wp = weight + (size_t)(g * OPG + lp) * Cpg * KK + t;
#pragma unroll
            for (int c = 0; c < 8; ++c) a[c] = (_Float16)wp[c * KK];
        }
        afrag[m] = a;
    }

    const float* offy = offset + (size_t)(b * 2 + 0) * (G * KK) * HW;
    const float* offx = offset + (size_t)(b * 2 + 1) * (G * KK) * HW;
    const float* mk   = mask + (size_t)b * (G * KK) * HW;

    // burst all offset/mask loads (sigmoid + tap-9 pad folded here)
    float dyv[2][5], dxv[2][5], msv[2][5];
#pragma unroll
    for (int tile = 0; tile < 2; ++tile) {
        const int wq  = wv * 64 + tile * 32 + lp;
        const int pix = h * W + wq;
#pragma unroll
        for (int m = 0; m < 5; ++m) {
            const int t  = 2 * m + hi;
            const int tt = (t > 8) ? 8 : t;
            const int idx0 = G * KK - 1 - (g * KK + tt);   // flipped tap axis
            dyv[tile][m] = offy[(size_t)idx0 * HW + pix];
            dxv[tile][m] = offx[(size_t)idx0 * HW + pix];
            const float mv = mk[(size_t)(g * KK + tt) * HW + pix];
            float s = 1.0f / (1.0f + __expf(-mv));
            msv[tile][m] = (t <= 8) ? s : 0.0f;
        }
    }

    __syncthreads();   // window ready

    // one tap: bilinear blend of 4 corners from the LDS window
    auto sample = [&](int t, int wq, float dy, float dx, float msig) -> f16x8 {
        const int tt = (t > 8) ? 8 : t;
        const int ki = (tt >= 3) + (tt >= 6);
        const int kj = tt - 3 * ki;

        const float py = (float)(h - PAD + ki) + dy;
        const float px = (float)(wq - PAD + kj) + dx;
        const float y0f = floorf(py), x0f = floorf(px);
        const float wy = py - y0f, wx = px - x0f;
        const int y0 = (int)y0f, x0 = (int)x0f;
        const bool vy0 = (y0 >= 0) & (y0 < H), vy1 = (y0 + 1 >= 0) & (y0 + 1 < H);
        const bool vx0 = (x0 >= 0) & (x0 < W), vx1 = (x0 + 1 >= 0) & (x0 + 1 < W);

        const float u   = vy0 ? (1.f - wy) * msig : 0.f;
        const float v   = vy1 ? wy * msig : 0.f;
        const float cx0 = vx0 ? (1.f - wx) : 0.f;
        const float cx1 = vx1 ? wx : 0.f;

        const int iy0 = y0 - h0;
        const int iy1 = iy0 + 1;
        const int i0 = min(max(iy0, 0), WROWS - 1);
        const int i1 = min(max(iy1, 0), WROWS - 1);
        const int xc0 = min(max(x0, 0), W - 1);
        const int xc1 = min(max(x0 + 1, 0), W - 1);

        uint4 v00 = win[i0 * WPITCH + xc0];
        uint4 v01 = win[i0 * WPITCH + xc1];
        uint4 v10 = win[i1 * WPITCH + xc0];
        uint4 v11 = win[i1 * WPITCH + xc1];

        const bool bad = (vy0 & ((unsigned)iy0 > (unsigned)(WROWS - 1))) |
                         (vy1 & ((unsigned)iy1 > (unsigned)(WROWS - 1)));
        if (__builtin_expect(__any((int)bad), 0)) {   // |dy| ~> 5 : p ~ 6e-7
            if (bad) {
                const int yc0 = min(max(y0, 0), H - 1);
                const int yc1 = min(max(y0 + 1, 0), H - 1);
                v00 = xb[yc0 * W + xc0];
                v01 = xb[yc0 * W + xc1];
                v10 = xb[yc1 * W + xc0];
                v11 = xb[yc1 * W + xc1];
            }
        }

        const float w00 = u * cx0, w01 = u * cx1, w10 = v * cx0, w11 = v * cx1;
        U4H a, bq, c, d; a.u = v00; bq.u = v01; c.u = v10; d.u = v11;
        const __half2 hw00 = __float2half2_rn(w00);
        const __half2 hw01 = __float2half2_rn(w01);
        const __half2 hw10 = __float2half2_rn(w10);
        const __half2 hw11 = __float2half2_rn(w11);
        U4H s;
#pragma unroll
        for (int i = 0; i < 4; ++i)
            s.h2[i] = __hfma2(hw00, a.h2[i],
                      __hfma2(hw01, bq.h2[i],
                      __hfma2(hw10, c.h2[i],
                      __hmul2(hw11, d.h2[i]))));
        return s.v;
    };

    f32x16 acc0 = {};
    f32x16 acc1 = {};
    {
        const int wq = wv * 64 + lp;
#pragma unroll
        for (int m = 0; m < 5; ++m)
            acc0 = __builtin_amdgcn_mfma_f32_32x32x16_f16(
                afrag[m], sample(2 * m + hi, wq, dyv[0][m], dxv[0][m], msv[0][m]), acc0, 0, 0, 0);
    }
    {
        const int wq = wv * 64 + 32 + lp;
#pragma unroll
        for (int m = 0; m < 5; ++m)
            acc1 = __builtin_amdgcn_mfma_f32_32x32x16_f16(
                afrag[m], sample(2 * m + hi, wq, dyv[1][m], dxv[1][m], msv[1][m]), acc1, 0, 0, 0);
    }

    // C layout: col = lp (pixel), row = (reg&3) + 8*(reg>>2) + 4*hi.
    // Useful rows 0..7 -> out channel d = reg + 4*hi (regs 0..3).
#pragma unroll
    for (int tile = 0; tile < 2; ++tile) {
        const int wq = wv * 64 + tile * 32 + lp;
#pragma unroll
        for (int r = 0; r < 4; ++r) {
            const int dd = r + 4 * hi;
            const float v = (tile == 0 ? acc0[r] : acc1[r]) + bias[g * OPG + dd];
            out[((size_t)b * OC + g * OPG + dd) * HW + h * W + wq] = v;
        }
    }
}

extern "C" void kernel_launch(void* const* d_in, const int* in_sizes, int n_in,
                              void* d_out, int out_size, void* d_ws, size_t ws_size,
                              hipStream_t stream) {
    const float* x      = (const float*)d_in[0];
    const float* offset = (const float*)d_in[1];
    const float* mask   = (const float*)d_in[2];
    const float* weight = (const float*)d_in[3];
    const float* bias   = (const float*)d_in[4];
    float* out = (float*)d_out;
    uint4* xt  = (uint4*)d_ws;   // B*G*HW * 16B = 32 MiB

    dim3 tgrid(H, G, B);
    transpose_kernel<<<tgrid, dim3(256), 0, stream>>>(x, xt);
    dcn_kernel<<<dim3(B * G * H / 2), dim3(512), 0, stream>>>(xt, offset, mask, weight, bias, out);
}

// Round 8
// 115.674 us; speedup vs baseline: 2.2797x; 2.2797x over previous
//
#include <hip/hip_runtime.h>
#include <hip/hip_fp16.h>

// Deformable Conv2d — MI355X, round 8
// vs round 7: SAME 2-rows-per-block / 13-row shared LDS window structure, but
// plain __launch_bounds__(512) — the (512,6) min-waves demand forced a 40-VGPR
// allocation and spilled ~90 regs/thread to scratch (WRITE_SIZE 64->432 MB,
// occupancy 4.9%). Compiler-default allocation (~68 VGPR) + LDS-bound
// 3 blocks/CU gives the intended 24 waves/CU.

#define KSZ 3
#define PAD 1

static constexpr int B   = 4;
static constexpr int Cin = 64;
static constexpr int H   = 256;
static constexpr int W   = 256;
static constexpr int G   = 8;
static constexpr int OC  = 64;
static constexpr int KK  = KSZ * KSZ;  // 9
static constexpr int Cpg = Cin / G;    // 8
static constexpr int OPG = OC / G;     // 8
static constexpr int HW  = H * W;
static constexpr int NXCD = 8;

static constexpr int WROWS  = 13;      // window rows: h_base-5 .. h_base+7
static constexpr int WUP    = 5;
static constexpr int WPITCH = 257;     // 16B slots/row

typedef _Float16 f16x8  __attribute__((ext_vector_type(8)));
typedef float    f32x16 __attribute__((ext_vector_type(16)));

union U4H {
    uint4 u;
    __half2 h2[4];
    _Float16 h[8];
    f16x8 v;
};

// ---- transpose: x [B,Cin,H,W] f32 -> xt [B,G,H,W,Cpg] fp16 (16B/pixel) ----
__global__ __launch_bounds__(256) void transpose_kernel(
    const float* __restrict__ x, uint4* __restrict__ xt)
{
    const int h = blockIdx.x, g = blockIdx.y, b = blockIdx.z;
    const int w = threadIdx.x;
    const int pix = h * W + w;
    const float* src = x + (size_t)(b * Cin + g * Cpg) * HW + pix;
    U4H v;
#pragma unroll
    for (int c = 0; c < 8; ++c) v.h[c] = (_Float16)src[(size_t)c * HW];
    xt[(size_t)(b * G + g) * HW + pix] = v.u;
}

// ---- main kernel: 512 threads, 2 output rows/block ----
__global__ __launch_bounds__(512) void dcn_kernel(
    const uint4* __restrict__ xt,
    const float* __restrict__ offset,
    const float* __restrict__ mask,
    const float* __restrict__ weight,
    const float* __restrict__ bias,
    float* __restrict__ out)
{
    __shared__ uint4 win[WROWS * WPITCH];   // 53,456 B -> 3 blocks/CU

    // XCD-chunked bijective swizzle over 4096 blocks (4096 % 8 == 0)
    const unsigned id = blockIdx.x;
    const unsigned wl = (id & (NXCD - 1)) * (gridDim.x / NXCD) + (id >> 3);
    const int p  = wl & (H / 2 - 1);          // row-pair index
    const int bg = wl >> 7;
    const int g  = bg & (G - 1);
    const int b  = bg >> 3;
    const int h_base = 2 * p;

    const int tid  = threadIdx.x;
    const int lane = tid & 63;
    const int wave = tid >> 6;                // 0..7
    const int row_sel = wave >> 2;            // 0 or 1 -> output row
    const int wv   = wave & 3;                // quarter within the row
    const int hi   = lane >> 5;               // tap parity in MFMA k dim
    const int lp   = lane & 31;               // A-row (out ch) / B-col (pixel)

    const int h  = h_base + row_sel;
    const int h0 = h_base - WUP;

    const uint4* xb = xt + (size_t)(b * G + g) * HW;

    // ---- stage the 13-row window (rows pre-clamped) ----
#pragma unroll
    for (int it = 0; it < 7; ++it) {
        const int k = it * 512 + tid;
        if (k < WROWS * 256) {
            const int i   = k >> 8;
            const int col = k & 255;
            const int wr  = min(max(h0 + i, 0), H - 1);
            win[i * WPITCH + col] = xb[wr * W + col];
        }
    }

    // A-fragments: weights, A[row=d][k=hi*8+c] -> tap 2m+hi, channel c.
    f16x8 afrag[5];
#pragma unroll
    for (int m = 0; m < 5; ++m) {
        f16x8 a = {};
        const int t = 2 * m + hi;
        if (lp < OPG && t < KK) {
            const float* wp = weight + (size_t)(g * OPG + lp) * Cpg * KK + t;
#pragma unroll
            for (int c = 0; c < 8; ++c) a[c] = (_Float16)wp[c * KK];
        }
        afrag[m] = a;
    }

    const float* offy = offset + (size_t)(b * 2 + 0) * (G * KK) * HW;
    const float* offx = offset + (size_t)(b * 2 + 1) * (G * KK) * HW;
    const float* mk   = mask + (size_t)b * (G * KK) * HW;

    // burst all offset/mask loads (sigmoid + tap-9 pad folded here)
    float dyv[2][5], dxv[2][5], msv[2][5];
#pragma unroll
    for (int tile = 0; tile < 2; ++tile) {
        const int wq  = wv * 64 + tile * 32 + lp;
        const int pix = h * W + wq;
#pragma unroll
        for (int m = 0; m < 5; ++m) {
            const int t  = 2 * m + hi;
            const int tt = (t > 8) ? 8 : t;
            const int idx0 = G * KK - 1 - (g * KK + tt);   // flipped tap axis
            dyv[tile][m] = offy[(size_t)idx0 * HW + pix];
            dxv[tile][m] = offx[(size_t)idx0 * HW + pix];
            const float mv = mk[(size_t)(g * KK + tt) * HW + pix];
            float s = 1.0f / (1.0f + __expf(-mv));
            msv[tile][m] = (t <= 8) ? s : 0.0f;
        }
    }

    __syncthreads();   // window ready

    // one tap: bilinear blend of 4 corners from the LDS window
    auto sample = [&](int t, int wq, float dy, float dx, float msig) -> f16x8 {
        const int tt = (t > 8) ? 8 : t;
        const int ki = (tt >= 3) + (tt >= 6);
        const int kj = tt - 3 * ki;

        const float py = (float)(h - PAD + ki) + dy;
        const float px = (float)(wq - PAD + kj) + dx;
        const float y0f = floorf(py), x0f = floorf(px);
        const float wy = py - y0f, wx = px - x0f;
        const int y0 = (int)y0f, x0 = (int)x0f;
        const bool vy0 = (y0 >= 0) & (y0 < H), vy1 = (y0 + 1 >= 0) & (y0 + 1 < H);
        const bool vx0 = (x0 >= 0) & (x0 < W), vx1 = (x0 + 1 >= 0) & (x0 + 1 < W);

        const float u   = vy0 ? (1.f - wy) * msig : 0.f;
        const float v   = vy1 ? wy * msig : 0.f;
        const float cx0 = vx0 ? (1.f - wx) : 0.f;
        const float cx1 = vx1 ? wx : 0.f;

        const int iy0 = y0 - h0;
        const int iy1 = iy0 + 1;
        const int i0 = min(max(iy0, 0), WROWS - 1);
        const int i1 = min(max(iy1, 0), WROWS - 1);
        const int xc0 = min(max(x0, 0), W - 1);
        const int xc1 = min(max(x0 + 1, 0), W - 1);

        uint4 v00 = win[i0 * WPITCH + xc0];
        uint4 v01 = win[i0 * WPITCH + xc1];
        uint4 v10 = win[i1 * WPITCH + xc0];
        uint4 v11 = win[i1 * WPITCH + xc1];

        const bool bad = (vy0 & ((unsigned)iy0 > (unsigned)(WROWS - 1))) |
                         (vy1 & ((unsigned)iy1 > (unsigned)(WROWS - 1)));
        if (__builtin_expect(__any((int)bad), 0)) {   // |dy| ~> 5 : p ~ 6e-7
            if (bad) {
                const int yc0 = min(max(y0, 0), H - 1);
                const int yc1 = min(max(y0 + 1, 0), H - 1);
                v00 = xb[yc0 * W + xc0];
                v01 = xb[yc0 * W + xc1];
                v10 = xb[yc1 * W + xc0];
                v11 = xb[yc1 * W + xc1];
            }
        }

        const float w00 = u * cx0, w01 = u * cx1, w10 = v * cx0, w11 = v * cx1;
        U4H a, bq, c, d; a.u = v00; bq.u = v01; c.u = v10; d.u = v11;
        const __half2 hw00 = __float2half2_rn(w00);
        const __half2 hw01 = __float2half2_rn(w01);
        const __half2 hw10 = __float2half2_rn(w10);
        const __half2 hw11 = __float2half2_rn(w11);
        U4H s;
#pragma unroll
        for (int i = 0; i < 4; ++i)
            s.h2[i] = __hfma2(hw00, a.h2[i],
                      __hfma2(hw01, bq.h2[i],
                      __hfma2(hw10, c.h2[i],
                      __hmul2(hw11, d.h2[i]))));
        return s.v;
    };

    f32x16 acc0 = {};
    f32x16 acc1 = {};
    {
        const int wq = wv * 64 + lp;
#pragma unroll
        for (int m = 0; m < 5; ++m)
            acc0 = __builtin_amdgcn_mfma_f32_32x32x16_f16(
                afrag[m], sample(2 * m + hi, wq, dyv[0][m], dxv[0][m], msv[0][m]), acc0, 0, 0, 0);
    }
    {
        const int wq = wv * 64 + 32 + lp;
#pragma unroll
        for (int m = 0; m < 5; ++m)
            acc1 = __builtin_amdgcn_mfma_f32_32x32x16_f16(
                afrag[m], sample(2 * m + hi, wq, dyv[1][m], dxv[1][m], msv[1][m]), acc1, 0, 0, 0);
    }

    // C layout: col = lp (pixel), row = (reg&3) + 8*(reg>>2) + 4*hi.
    // Useful rows 0..7 -> out channel d = reg + 4*hi (regs 0..3).
#pragma unroll
    for (int tile = 0; tile < 2; ++tile) {
        const int wq = wv * 64 + tile * 32 + lp;
#pragma unroll
        for (int r = 0; r < 4; ++r) {
            const int dd = r + 4 * hi;
            const float v = (tile == 0 ? acc0[r] : acc1[r]) + bias[g * OPG + dd];
            out[((size_t)b * OC + g * OPG + dd) * HW + h * W + wq] = v;
        }
    }
}

extern "C" void kernel_launch(void* const* d_in, const int* in_sizes, int n_in,
                              void* d_out, int out_size, void* d_ws, size_t ws_size,
                              hipStream_t stream) {
    const float* x      = (const float*)d_in[0];
    const float* offset = (const float*)d_in[1];
    const float* mask   = (const float*)d_in[2];
    const float* weight = (const float*)d_in[3];
    const float* bias   = (const float*)d_in[4];
    float* out = (float*)d_out;
    uint4* xt  = (uint4*)d_ws;   // B*G*HW * 16B = 32 MiB

    dim3 tgrid(H, G, B);
    transpose_kernel<<<tgrid, dim3(256), 0, stream>>>(x, xt);
    dcn_kernel<<<dim3(B * G * H / 2), dim3(512), 0, stream>>>(xt, offset, mask, weight, bias, out);
}